// Round 1
// baseline (544.365 us; speedup 1.0000x reference)
//
#include <hip/hip_runtime.h>
#include <stdint.h>

typedef __attribute__((ext_vector_type(8))) short short8;
typedef __attribute__((ext_vector_type(4))) float f32x4;
typedef __attribute__((ext_vector_type(8))) unsigned short u16x8;

#define DEV static __device__ __forceinline__

DEV unsigned short f2bf(float f) {
  union { float f; uint32_t u; } v; v.f = f;
  uint32_t r = v.u + 0x7FFFu + ((v.u >> 16) & 1u);
  return (unsigned short)(r >> 16);
}

DEV void gload16(const void* g, void* l) {
  __builtin_amdgcn_global_load_lds(
      (const __attribute__((address_space(1))) void*)g,
      (__attribute__((address_space(3))) void*)l, 16, 0, 0);
}

// ---------------- cast x (f32 -> bf16), 8 elems/thread ----------------
__global__ void cast_x_kernel(const float* __restrict__ x, unsigned short* __restrict__ xb) {
  int i = blockIdx.x * 256 + threadIdx.x;
  f32x4 a = ((const f32x4*)x)[2 * i];
  f32x4 b = ((const f32x4*)x)[2 * i + 1];
  u16x8 o;
  o[0] = f2bf(a[0]); o[1] = f2bf(a[1]); o[2] = f2bf(a[2]); o[3] = f2bf(a[3]);
  o[4] = f2bf(b[0]); o[5] = f2bf(b[1]); o[6] = f2bf(b[2]); o[7] = f2bf(b[3]);
  ((u16x8*)xb)[i] = o;
}

// ---------------- transpose + cast W (K,N)f32 -> Wt (N,K)bf16 ----------------
__global__ void transpose_w_kernel(const float* __restrict__ Wq, const float* __restrict__ Wk,
                                   const float* __restrict__ Wv, const float* __restrict__ Wo,
                                   unsigned short* __restrict__ wt) {
  __shared__ float tile[64][65];
  int z = blockIdx.z;
  const float* W = (z == 0) ? Wq : (z == 1) ? Wk : (z == 2) ? Wv : Wo;
  unsigned short* dst = wt + (size_t)z * 1024 * 1024;
  int bn = blockIdx.x, bk = blockIdx.y;
  int t = threadIdx.x;
  int c = t & 63, rr = t >> 6;
#pragma unroll
  for (int p = 0; p < 16; ++p) {
    int r = p * 4 + rr;
    tile[r][c] = W[(size_t)(bk * 64 + r) * 1024 + bn * 64 + c];
  }
  __syncthreads();
#pragma unroll
  for (int p = 0; p < 16; ++p) {
    int r2 = p * 4 + rr;
    dst[(size_t)(bn * 64 + r2) * 1024 + bk * 64 + c] = f2bf(tile[c][r2]);
  }
}

// ---------------- bf16 GEMM: C(8192x1024) = A(8192x1024) * Bt(1024x1024,N-major)^T ----
// MODE 0: f32 out, row-major (to d_out)
// MODE 1: bf16 out to (B,H,S,Dh)
// MODE 2: bf16 out transposed to (B,H,Dh,S)
template <int MODE>
__global__ __launch_bounds__(256, 2) void gemm_bt(const unsigned short* __restrict__ A,
                                                  const unsigned short* __restrict__ Bt,
                                                  void* __restrict__ dst) {
  constexpr int K = 1024;
  __shared__ __align__(16) unsigned short As[128 * 64];
  __shared__ __align__(16) unsigned short Bs[128 * 64];
  int bn = blockIdx.x, bm = blockIdx.y;
  int tid = threadIdx.x, lane = tid & 63, w = tid >> 6;
  int wr = w >> 1, wc = w & 1;
  f32x4 acc[4][4] = {};

  // staging geometry: 16KB per tile = 16 wave-calls of 1024B; wave w does ci = w*4..w*4+3
  int sr[4], soff[4];
#pragma unroll
  for (int i = 0; i < 4; ++i) {
    int ci = w * 4 + i;
    int r = ci * 8 + (lane >> 3);
    int cc = lane & 7;
    int scc = cc ^ (r & 7);
    sr[i] = r;
    soff[i] = scc * 8;
  }
  const unsigned short* Arow = A + (size_t)(bm * 128) * K;
  const unsigned short* Brow = Bt + (size_t)(bn * 128) * K;

  for (int k0 = 0; k0 < K; k0 += 64) {
#pragma unroll
    for (int i = 0; i < 4; ++i) {
      gload16(Arow + (size_t)sr[i] * K + k0 + soff[i], As + (w * 4 + i) * 512);
      gload16(Brow + (size_t)sr[i] * K + k0 + soff[i], Bs + (w * 4 + i) * 512);
    }
    __syncthreads();
    short8 af[2][4], bfr[2][4];
#pragma unroll
    for (int c = 0; c < 2; ++c) {
#pragma unroll
      for (int m = 0; m < 4; ++m) {
        int cc = (lane >> 4) + 4 * c;
        int ra = wr * 64 + m * 16 + (lane & 15);
        af[c][m] = *(const short8*)(As + ra * 64 + ((cc ^ (ra & 7)) * 8));
        int rb = wc * 64 + m * 16 + (lane & 15);
        bfr[c][m] = *(const short8*)(Bs + rb * 64 + ((cc ^ (rb & 7)) * 8));
      }
    }
#pragma unroll
    for (int c = 0; c < 2; ++c)
#pragma unroll
      for (int m = 0; m < 4; ++m)
#pragma unroll
        for (int n = 0; n < 4; ++n)
          acc[m][n] = __builtin_amdgcn_mfma_f32_16x16x32_bf16(af[c][m], bfr[c][n], acc[m][n], 0, 0, 0);
    __syncthreads();
  }

  int rbase = bm * 128 + wr * 64;
  int cbase = bn * 128 + wc * 64;
#pragma unroll
  for (int m = 0; m < 4; ++m)
#pragma unroll
    for (int n = 0; n < 4; ++n) {
      int row0 = rbase + m * 16 + (lane >> 4) * 4;
      int col = cbase + n * 16 + (lane & 15);
#pragma unroll
      for (int reg = 0; reg < 4; ++reg) {
        int row = row0 + reg;
        float v = acc[m][n][reg];
        if (MODE == 0) {
          ((float*)dst)[(size_t)row * 1024 + col] = v;
        } else {
          int b = row >> 12, s = row & 4095;
          int h = col >> 6, d = col & 63;
          if (MODE == 1)
            ((unsigned short*)dst)[((size_t)(b * 16 + h) * 4096 + s) * 64 + d] = f2bf(v);
          else
            ((unsigned short*)dst)[((size_t)(b * 16 + h) * 64 + d) * 4096 + s] = f2bf(v);
        }
      }
    }
}

// ---------------- sparse attention ----------------
// grid: (64 qblocks, 32 b*h); block 256 = 4 waves; wave w owns q rows qb*64+w*16..+15
__global__ void attn_kernel(const unsigned short* __restrict__ Qh,
                            const unsigned short* __restrict__ Kh,
                            const unsigned short* __restrict__ Vth,
                            const int* __restrict__ bidx,
                            unsigned short* __restrict__ attn_out) {
  __shared__ __align__(16) unsigned short Ks[64 * 64];
  __shared__ __align__(16) unsigned short Vts[64 * 64];
  __shared__ __align__(16) unsigned short Pl[4][16][72];  // 144B rows: 16B-aligned, 2-way banks
  int qb = blockIdx.x, bh = blockIdx.y;
  int h = bh & 15;
  int tid = threadIdx.x, lane = tid & 63, w = tid >> 6;
  float slope = exp2f(-0.5f * (float)(h + 1));
  const float scale = 0.125f;

  int qrow = qb * 64 + w * 16 + (lane & 15);
  const unsigned short* qptr = Qh + ((size_t)bh * 4096 + qrow) * 64 + (lane >> 4) * 8;
  short8 qf0 = *(const short8*)qptr;
  short8 qf1 = *(const short8*)(qptr + 32);

  int list[13];
  int nkb;
  if (qb == 0) {
    nkb = 64;
  } else {
    nkb = 1;
    list[0] = 0;
#pragma unroll
    for (int j = 0; j < 12; ++j) {
      int v = bidx[qb * 12 + j];
      if (v >= 0) list[nkb++] = v;
    }
  }

  float m[4], l[4];
  f32x4 accO[4] = {};
#pragma unroll
  for (int r = 0; r < 4; ++r) { m[r] = -1e30f; l[r] = 0.f; }
  int qpos0 = qb * 64 + w * 16 + (lane >> 4) * 4;

  for (int it = 0; it < nkb; ++it) {
    int kb = (qb == 0) ? it : list[it];
    // stage K (contiguous 8KB) and Vt (64 rows x 128B) with inverse-swizzled source
    const unsigned short* kbase = Kh + ((size_t)bh * 4096 + kb * 64) * 64;
    const unsigned short* vbase = Vth + (size_t)bh * 64 * 4096 + kb * 64;
#pragma unroll
    for (int i = 0; i < 2; ++i) {
      int ci = w * 2 + i;
      int r = ci * 8 + (lane >> 3);
      int scc = (lane & 7) ^ (r & 7);
      gload16(kbase + r * 64 + scc * 8, Ks + ci * 512);
      gload16(vbase + (size_t)r * 4096 + scc * 8, Vts + ci * 512);
    }
    __syncthreads();

    // QK^T + bias
    float sv[4][4];
#pragma unroll
    for (int ct = 0; ct < 4; ++ct) {
      int kr = ct * 16 + (lane & 15);
      short8 kf0 = *(const short8*)(Ks + kr * 64 + (((lane >> 4) ^ (kr & 7)) * 8));
      short8 kf1 = *(const short8*)(Ks + kr * 64 + ((((lane >> 4) + 4) ^ (kr & 7)) * 8));
      f32x4 s = __builtin_amdgcn_mfma_f32_16x16x32_bf16(qf0, kf0, (f32x4){0.f, 0.f, 0.f, 0.f}, 0, 0, 0);
      s = __builtin_amdgcn_mfma_f32_16x16x32_bf16(qf1, kf1, s, 0, 0, 0);
      int kpos = kb * 64 + ct * 16 + (lane & 15);
#pragma unroll
      for (int reg = 0; reg < 4; ++reg) {
        float dp = fabsf((float)(qpos0 + reg - kpos));
        sv[ct][reg] = s[reg] * scale - slope * dp;
      }
    }
    // row max across 16 lanes + 4 col-tiles
    float sf[4];
#pragma unroll
    for (int reg = 0; reg < 4; ++reg) {
      float v = fmaxf(fmaxf(sv[0][reg], sv[1][reg]), fmaxf(sv[2][reg], sv[3][reg]));
#pragma unroll
      for (int off = 1; off < 16; off <<= 1) v = fmaxf(v, __shfl_xor(v, off, 64));
      float mn = fmaxf(m[reg], v);
      sf[reg] = __expf(m[reg] - mn);
      m[reg] = mn;
    }
    float psum[4] = {0.f, 0.f, 0.f, 0.f};
#pragma unroll
    for (int ct = 0; ct < 4; ++ct)
#pragma unroll
      for (int reg = 0; reg < 4; ++reg) {
        float p = __expf(sv[ct][reg] - m[reg]);
        psum[reg] += p;
        Pl[w][(lane >> 4) * 4 + reg][ct * 16 + (lane & 15)] = f2bf(p);
      }
#pragma unroll
    for (int reg = 0; reg < 4; ++reg) {
      float v = psum[reg];
#pragma unroll
      for (int off = 1; off < 16; off <<= 1) v += __shfl_xor(v, off, 64);
      l[reg] = l[reg] * sf[reg] + v;
    }
#pragma unroll
    for (int dt = 0; dt < 4; ++dt)
#pragma unroll
      for (int reg = 0; reg < 4; ++reg) accO[dt][reg] *= sf[reg];
    __syncthreads();  // P visible (and wave-ordered) before A-fragment reads

    short8 pa0 = *(const short8*)(&Pl[w][lane & 15][(lane >> 4) * 8]);
    short8 pa1 = *(const short8*)(&Pl[w][lane & 15][(lane >> 4) * 8 + 32]);
#pragma unroll
    for (int dt = 0; dt < 4; ++dt) {
      int dr = dt * 16 + (lane & 15);
      short8 vf0 = *(const short8*)(Vts + dr * 64 + (((lane >> 4) ^ (dr & 7)) * 8));
      short8 vf1 = *(const short8*)(Vts + dr * 64 + ((((lane >> 4) + 4) ^ (dr & 7)) * 8));
      accO[dt] = __builtin_amdgcn_mfma_f32_16x16x32_bf16(pa0, vf0, accO[dt], 0, 0, 0);
      accO[dt] = __builtin_amdgcn_mfma_f32_16x16x32_bf16(pa1, vf1, accO[dt], 0, 0, 0);
    }
    __syncthreads();  // protect Ks/Vts before next stage
  }

  int b = bh >> 4;
#pragma unroll
  for (int dt = 0; dt < 4; ++dt)
#pragma unroll
    for (int reg = 0; reg < 4; ++reg) {
      int row = qb * 64 + w * 16 + (lane >> 4) * 4 + reg;
      int col = h * 64 + dt * 16 + (lane & 15);
      attn_out[((size_t)b * 4096 + row) * 1024 + col] = f2bf(accO[dt][reg] / l[reg]);
    }
}

extern "C" void kernel_launch(void* const* d_in, const int* in_sizes, int n_in,
                              void* d_out, int out_size, void* d_ws, size_t ws_size,
                              hipStream_t stream) {
  const float* x = (const float*)d_in[0];
  const float* Wq = (const float*)d_in[1];
  const float* Wk = (const float*)d_in[2];
  const float* Wv = (const float*)d_in[3];
  const float* Wo = (const float*)d_in[4];
  const int* bidx = (const int*)d_in[5];

  char* ws = (char*)d_ws;
  unsigned short* xb = (unsigned short*)(ws);
  unsigned short* wt = (unsigned short*)(ws + 16777216);
  unsigned short* Qb = (unsigned short*)(ws + 25165824);
  unsigned short* Kb = (unsigned short*)(ws + 41943040);
  unsigned short* Vtb = (unsigned short*)(ws + 58720256);
  unsigned short* attnb = (unsigned short*)(ws + 75497472);

  cast_x_kernel<<<4096, 256, 0, stream>>>(x, xb);
  transpose_w_kernel<<<dim3(16, 16, 4), 256, 0, stream>>>(Wq, Wk, Wv, Wo, wt);
  gemm_bt<1><<<dim3(8, 64), 256, 0, stream>>>(xb, wt, Qb);
  gemm_bt<1><<<dim3(8, 64), 256, 0, stream>>>(xb, wt + 1048576, Kb);
  gemm_bt<2><<<dim3(8, 64), 256, 0, stream>>>(xb, wt + 2097152, Vtb);
  attn_kernel<<<dim3(64, 32), 256, 0, stream>>>(Qb, Kb, Vtb, bidx, attnb);
  gemm_bt<0><<<dim3(8, 64), 256, 0, stream>>>(attnb, wt + 3145728, (float*)d_out);
}